// Round 9
// baseline (1975.466 us; speedup 1.0000x reference)
//
#include <hip/hip_runtime.h>

#define DIM 1024
#define HEADS 16
#define HDIM 64
#define SEQ 2048
// 0.125 * log2(e) — folded into A's projection epilogue
#define SCLOG2 0.18033688011112042f

typedef __attribute__((ext_vector_type(8))) short short8;
typedef __attribute__((ext_vector_type(4))) float f32x4;
typedef __attribute__((ext_vector_type(16))) float f32x16;
typedef __attribute__((ext_vector_type(4))) int i32x4;

static __device__ __forceinline__ unsigned short f2bf(float f){
  union { float f; unsigned int u; } v; v.f = f;
  unsigned int r = v.u + 0x7fffu + ((v.u >> 16) & 1u);
  return (unsigned short)(r >> 16);
}

static __device__ __forceinline__ int cvtpk(float lo, float hi){
  int r;
  asm("v_cvt_pk_bf16_f32 %0, %1, %2" : "=v"(r) : "v"(lo), "v"(hi));
  return r;
}
static __device__ __forceinline__ void swap32(int& a, int& b){
  asm("v_permlane32_swap_b32 %0, %1" : "+v"(a), "+v"(b));
}

__device__ __forceinline__ void gl_lds16(const unsigned short* g, unsigned short* l){
  __builtin_amdgcn_global_load_lds((const __attribute__((address_space(1))) void*)g,
                                   (__attribute__((address_space(3))) void*)l, 16, 0, 0);
}

// ---------------- fused cast: all 5 inputs -> contiguous bf16 ws ----------------
#define CAST_TOTAL 3145728

__global__ __launch_bounds__(256)
void cast_all(const float* __restrict__ x, const float* __restrict__ x2,
              const float* __restrict__ wq, const float* __restrict__ wa,
              const float* __restrict__ wkv, unsigned short* __restrict__ out)
{
  for (int i = blockIdx.x*256 + threadIdx.x; i < CAST_TOTAL; i += gridDim.x*256){
    const float* src; int off;
    if      (i < 1048576){ src = x;   off = i; }
    else if (i < 2097152){ src = x2;  off = i - 1048576; }
    else if (i < 2359296){ src = wq;  off = i - 2097152; }
    else if (i < 2621440){ src = wa;  off = i - 2359296; }
    else                 { src = wkv; off = i - 2621440; }
    float4 v = ((const float4*)src)[off];
    ushort4 o;
    o.x = f2bf(v.x); o.y = f2bf(v.y); o.z = f2bf(v.z); o.w = f2bf(v.w);
    ((ushort4*)out)[i] = o;
  }
}

// ---------------- merged GEMM: all three projections in one dispatch ----------------
#define GK 1024

__global__ __launch_bounds__(256)
void gemm_all(const unsigned short* __restrict__ xb,  const unsigned short* __restrict__ x2b,
              const unsigned short* __restrict__ Wqb, const unsigned short* __restrict__ Wab,
              const unsigned short* __restrict__ Wkvb,
              unsigned short* __restrict__ Qw, unsigned short* __restrict__ Aw,
              unsigned short* __restrict__ Kw, unsigned short* __restrict__ Vwt)
{
  __shared__ unsigned short Ald[128*64];
  __shared__ unsigned short Bld[128*64];
  const int tid  = threadIdx.x;
  const int lane = tid & 63;
  const int wid  = tid >> 6;
  const int l15 = lane & 15, l4 = lane >> 4;
  const int wm = wid >> 1, wn = wid & 1;

  const int bid = blockIdx.x;
  const unsigned short *Abuf, *Bbuf;
  int mbase, nbase, isA;
  if (bid < 768){
    int nb = bid % 24, mb = bid / 24;
    nbase = nb*128; mbase = mb*128; isA = 0;
    Abuf = xb;
    Bbuf = (nbase < 1024) ? (Wqb + (size_t)nbase*GK) : (Wkvb + (size_t)(nbase-1024)*GK);
  } else {
    int b2 = bid - 768;
    int nb = b2 & 7, mb = b2 >> 3;
    nbase = nb*128; mbase = mb*128; isA = 1;
    Abuf = x2b;
    Bbuf = Wab + (size_t)nbase*GK;
  }

  const int srow = wid*32 + (lane >> 3);
  const int scol = (lane & 7)*8;
  const unsigned short* gA = Abuf + (size_t)(mbase + srow)*GK + scol;
  const unsigned short* gB = Bbuf + (size_t)srow*GK + scol;
  unsigned short* lA = Ald + (wid*32)*64;
  unsigned short* lB = Bld + (wid*32)*64;

  f32x4 acc[4][4];
  #pragma unroll
  for (int i=0;i<4;i++)
    #pragma unroll
    for(int j=0;j<4;j++) acc[i][j] = (f32x4){0.f,0.f,0.f,0.f};

  for (int kt = 0; kt < GK; kt += 64){
    __syncthreads();
    #pragma unroll
    for (int i=0;i<4;++i){
      gl_lds16(gA + (size_t)(i*8)*GK + kt, lA + i*8*64);
      gl_lds16(gB + (size_t)(i*8)*GK + kt, lB + i*8*64);
    }
    __syncthreads();
    #pragma unroll
    for (int kc = 0; kc < 2; ++kc){
      short8 af[4], bf[4];
      #pragma unroll
      for (int mt=0; mt<4; ++mt)
        af[mt] = *(const short8*)(Ald + (wm*64 + mt*16 + l15)*64 + kc*32 + l4*8);
      #pragma unroll
      for (int nt=0; nt<4; ++nt)
        bf[nt] = *(const short8*)(Bld + (wn*64 + nt*16 + l15)*64 + kc*32 + l4*8);
      #pragma unroll
      for (int mt=0; mt<4; ++mt)
        #pragma unroll
        for (int nt=0; nt<4; ++nt)
          acc[mt][nt] = __builtin_amdgcn_mfma_f32_16x16x32_bf16(af[mt], bf[nt], acc[mt][nt], 0,0,0);
    }
  }

  const float scale = isA ? SCLOG2 : 1.0f;
  #pragma unroll
  for (int mt=0; mt<4; ++mt){
    int mrow = mbase + wm*64 + mt*16 + l4*4;
    int b = mrow >> 11, nblk = mrow & 2047;
    #pragma unroll
    for (int nt=0; nt<4; ++nt){
      int col = nbase + wn*64 + nt*16 + l15;
      if (isA){
        int h = col >> 6, d = col & 63;
        #pragma unroll
        for (int r=0; r<4; ++r)
          Aw[((size_t)((b*HEADS + h)*SEQ + nblk + r))*HDIM + d] = f2bf(acc[mt][nt][r] * scale);
      } else if (col < 1024){
        int h = col >> 6, d = col & 63;
        #pragma unroll
        for (int r=0; r<4; ++r)
          Qw[((size_t)((b*HEADS + h)*SEQ + nblk + r))*HDIM + d] = f2bf(acc[mt][nt][r]);
      } else if (col < 2048){
        int c2 = col - 1024, h = c2 >> 6, d = c2 & 63;
        #pragma unroll
        for (int r=0; r<4; ++r)
          Kw[((size_t)((b*HEADS + h)*SEQ + nblk + r))*HDIM + d] = f2bf(acc[mt][nt][r]);
      } else {
        int c2 = col - 2048, h = c2 >> 6, d = c2 & 63;
        ushort4 pk;
        pk.x = f2bf(acc[mt][nt][0]);
        pk.y = f2bf(acc[mt][nt][1]);
        pk.z = f2bf(acc[mt][nt][2]);
        pk.w = f2bf(acc[mt][nt][3]);
        *(ushort4*)(Vwt + ((size_t)((b*HEADS + h)*HDIM + d))*SEQ + nblk) = pk;
      }
    }
  }
}

// ---------------- barrier-free fused flash attention ----------
// Direct global->register K/V loads (no LDS staging, no K-loop barriers).
// 8 waves: qw = wid&1 (32 q-rows), g = wid>>1 (kv quarter: keys g*512..+512, 8 tiles of 64)
// Merge: two-stage pairwise tree through LDS. mode 0: Y^T bf16; mode 1: fp32 out.
#define RSTRIDE 2144   // 64*33 floats + 32 sums per merge region

__global__ __launch_bounds__(512, 8)
void attn_pass(const unsigned short* __restrict__ Qb,
               const unsigned short* __restrict__ Kb,
               const unsigned short* __restrict__ Vtb,
               unsigned short* __restrict__ ytb,
               float* __restrict__ outf,
               int mode)
{
  __shared__ __align__(16) float LDSf[4*RSTRIDE];   // 34304 B
  const int tid = threadIdx.x, lane = tid & 63, wid = tid >> 6;
  const int l31 = lane & 31, l5 = lane >> 5;
  const int qw = wid & 1, g = wid >> 1;

  // XCD-aware decode: 4 bh per XCD, all 32 q-blocks of a bh on one XCD
  const int bid = blockIdx.x;
  const int cx = bid & 7, j = bid >> 3;
  const int bh = cx*4 + (j >> 5);
  const int qb = j & 31;
  const int q0 = qb*64 + qw*32;
  const size_t base = (size_t)bh * SEQ * HDIM;

  // Q^T B-fragments (col q = l31, k-rows d = db*16 + l5*8 ..+8)
  short8 qf[4];
  #pragma unroll
  for (int db=0; db<4; ++db)
    qf[db] = *(const short8*)(Qb + base + (size_t)(q0 + l31)*HDIM + db*16 + l5*8);

  // per-lane offsets (uniform base + 32-bit lane offset -> saddr form)
  const unsigned short* kq = Kb  + base + (size_t)g*512*HDIM;
  const unsigned short* vq = Vtb + base + (size_t)g*512;
  int koff[8], voff[8];
  #pragma unroll
  for (int f=0; f<8; ++f){
    int kb = f >> 2, db = f & 3;
    koff[f] = (kb*32 + l31)*HDIM + db*16 + l5*8;
    int db2 = f >> 2, kb2 = f & 3;
    voff[f] = (db2*32 + l31)*SEQ + kb2*16 + l5*8;
  }

  f32x16 oo0, oo1, ssum;
  #pragma unroll
  for (int r=0;r<16;++r){ oo0[r]=0.f; oo1[r]=0.f; ssum[r]=0.f; }
  short8 ones;
  #pragma unroll
  for (int jj=0;jj<8;++jj) ones[jj] = (short)0x3F80;

  for (int t = 0; t < 8; ++t){
    const unsigned short* kt = kq + t*(64*HDIM);
    const unsigned short* vt = vq + t*64;
    short8 kf[8], vf[8];
    #pragma unroll
    for (int f=0; f<8; ++f) kf[f] = *(const short8*)(kt + koff[f]);
    #pragma unroll
    for (int f=0; f<8; ++f) vf[f] = *(const short8*)(vt + voff[f]);

    #pragma unroll
    for (int kb=0; kb<2; ++kb){
      f32x16 sacc;
      #pragma unroll
      for (int r=0;r<16;++r) sacc[r]=0.f;
      #pragma unroll
      for (int db=0; db<4; ++db)
        sacc = __builtin_amdgcn_mfma_f32_32x32x16_bf16(kf[kb*4+db], qf[db], sacc, 0,0,0);

      float p[16];
      #pragma unroll
      for (int r=0;r<16;++r)
        p[r] = __builtin_amdgcn_exp2f(sacc[r]);   // scale pre-folded into A projection

      #pragma unroll
      for (int c=0; c<2; ++c){
        const int pb = c*8;
        int a0 = cvtpk(p[pb+0], p[pb+1]);
        int b0 = cvtpk(p[pb+4], p[pb+5]);
        int a1 = cvtpk(p[pb+2], p[pb+3]);
        int b1 = cvtpk(p[pb+6], p[pb+7]);
        swap32(a0, b0);
        swap32(a1, b1);
        i32x4 pav; pav[0]=a0; pav[1]=a1; pav[2]=b0; pav[3]=b1;
        short8 paf = *(short8*)&pav;
        const int kb2 = kb*2 + c;
        ssum = __builtin_amdgcn_mfma_f32_32x32x16_bf16(ones, paf, ssum, 0,0,0);
        oo0 = __builtin_amdgcn_mfma_f32_32x32x16_bf16(vf[0*4+kb2], paf, oo0, 0,0,0);
        oo1 = __builtin_amdgcn_mfma_f32_32x32x16_bf16(vf[1*4+kb2], paf, oo1, 0,0,0);
      }
    }
  }

  // ---- two-stage pairwise merge of the 4 kv quarters (per qw) ----
  float* reg0 = LDSf + (qw*2+0)*RSTRIDE;
  float* reg1 = LDSf + (qw*2+1)*RSTRIDE;

  // stage A: g=1 -> reg0, g=3 -> reg1
  if (g == 1 || g == 3){
    float* R = (g == 1) ? reg0 : reg1;
    #pragma unroll
    for (int r=0;r<16;++r){
      int d0 = (r&3) + 8*(r>>2) + 4*l5;
      R[d0*33 + l31]      = oo0[r];
      R[(d0+32)*33 + l31] = oo1[r];
    }
    R[2112 + l31] = ssum[0];
  }
  __syncthreads();
  if (g == 0 || g == 2){
    const float* R = (g == 0) ? reg0 : reg1;
    #pragma unroll
    for (int r=0;r<16;++r){
      int d0 = (r&3) + 8*(r>>2) + 4*l5;
      oo0[r] += R[d0*33 + l31];
      oo1[r] += R[(d0+32)*33 + l31];
    }
    ssum[0] += R[2112 + l31];
  }
  // stage B: g=2 writes its pair-sum into reg1
  if (g == 2){
    #pragma unroll
    for (int r=0;r<16;++r){
      int d0 = (r&3) + 8*(r>>2) + 4*l5;
      reg1[d0*33 + l31]      = oo0[r];
      reg1[(d0+32)*33 + l31] = oo1[r];
    }
    reg1[2112 + l31] = ssum[0];
  }
  __syncthreads();

  if (g == 0){
    #pragma unroll
    for (int r=0;r<16;++r){
      int d0 = (r&3) + 8*(r>>2) + 4*l5;
      oo0[r] += reg1[d0*33 + l31];
      oo1[r] += reg1[(d0+32)*33 + l31];
    }
    ssum[0] += reg1[2112 + l31];
    const float rinv = 1.0f / ssum[0];

    if (mode == 0){
      #pragma unroll
      for (int r=0;r<16;++r){
        int d0 = (r&3) + 8*(r>>2) + 4*l5;
        ytb[base + (size_t)(d0)*SEQ + q0 + l31]    = f2bf(oo0[r]*rinv);
        ytb[base + (size_t)(d0+32)*SEQ + q0 + l31] = f2bf(oo1[r]*rinv);
      }
    } else {
      // final scaled values -> reg0 for coalesced cooperative store
      #pragma unroll
      for (int r=0;r<16;++r){
        int d0 = (r&3) + 8*(r>>2) + 4*l5;
        reg0[d0*33 + l31]      = oo0[r]*rinv;
        reg0[(d0+32)*33 + l31] = oo1[r]*rinv;
      }
    }
  }

  if (mode == 1){
    __syncthreads();
    const int b = bh >> 4, h = bh & 15;
    const int ql = tid >> 3;              // 0..63 block-local q
    const int d8 = (tid & 7)*8;
    const float* R = LDSf + ((ql >> 5)*2)*RSTRIDE;
    const int q32 = ql & 31;
    float v[8];
    #pragma unroll
    for (int i=0;i<8;++i) v[i] = R[(d8+i)*33 + q32];
    float* drow = outf + ((size_t)(b*SEQ + qb*64 + ql))*DIM + h*HDIM + d8;
    *(float4*)(drow)     = (float4){v[0],v[1],v[2],v[3]};
    *(float4*)(drow + 4) = (float4){v[4],v[5],v[6],v[7]};
  }
}

extern "C" void kernel_launch(void* const* d_in, const int* in_sizes, int n_in,
                              void* d_out, int out_size, void* d_ws, size_t ws_size,
                              hipStream_t stream) {
  const float* x   = (const float*)d_in[0];
  const float* x2  = (const float*)d_in[1];
  const float* Wq  = (const float*)d_in[2];
  const float* Wa  = (const float*)d_in[3];
  const float* Wkv = (const float*)d_in[4];
  float* out = (float*)d_out;

  unsigned short* ws = (unsigned short*)d_ws;
  unsigned short* xb   = ws;                      // 4096*1024
  unsigned short* x2b  = xb   + 4096*1024;
  unsigned short* Wqb  = x2b  + 4096*1024;        // 1024*1024
  unsigned short* Wab  = Wqb  + 1024*1024;
  unsigned short* Wkvb = Wab  + 1024*1024;        // 2048*1024
  unsigned short* Qw   = Wkvb + 2048*1024;        // BHND = 4194304 each
  unsigned short* Aw   = Qw   + 4194304;
  unsigned short* Kw   = Aw   + 4194304;
  unsigned short* Vwt  = Kw   + 4194304;          // V^T [bh][d][n] (direct from gemm)
  unsigned short* Ywt  = xb;                      // Y^T [bh][d][n] (xb dead after gemm)

  cast_all<<<dim3(3072), dim3(256), 0, stream>>>(x, x2, Wq, Wa, Wkv, ws);

  gemm_all<<<dim3(1024), dim3(256), 0, stream>>>(xb, x2b, Wqb, Wab, Wkvb, Qw, Aw, Kw, Vwt);

  // pass 1: Y^T = (softmax(A k^T s) v)^T  -- written directly transposed
  attn_pass<<<dim3(1024), dim3(512), 0, stream>>>(Aw, Kw, Vwt, Ywt, nullptr, 0);

  // pass 2: out = softmax(q A^T s) Y
  attn_pass<<<dim3(1024), dim3(512), 0, stream>>>(Qw, Aw, Ywt, nullptr, out, 1);
}

// Round 10
// 157.603 us; speedup vs baseline: 12.5344x; 12.5344x over previous
//
#include <hip/hip_runtime.h>

#define DIM 1024
#define HEADS 16
#define HDIM 64
#define SEQ 2048
// 0.125 * log2(e) — folded into A's projection epilogue
#define SCLOG2 0.18033688011112042f

typedef __attribute__((ext_vector_type(8))) short short8;
typedef __attribute__((ext_vector_type(4))) float f32x4;
typedef __attribute__((ext_vector_type(16))) float f32x16;
typedef __attribute__((ext_vector_type(4))) int i32x4;

static __device__ __forceinline__ unsigned short f2bf(float f){
  union { float f; unsigned int u; } v; v.f = f;
  unsigned int r = v.u + 0x7fffu + ((v.u >> 16) & 1u);
  return (unsigned short)(r >> 16);
}

static __device__ __forceinline__ int cvtpk(float lo, float hi){
  int r;
  asm("v_cvt_pk_bf16_f32 %0, %1, %2" : "=v"(r) : "v"(lo), "v"(hi));
  return r;
}
static __device__ __forceinline__ void swap32(int& a, int& b){
  asm("v_permlane32_swap_b32 %0, %1" : "+v"(a), "+v"(b));
}

__device__ __forceinline__ void gl_lds16(const unsigned short* g, unsigned short* l){
  __builtin_amdgcn_global_load_lds((const __attribute__((address_space(1))) void*)g,
                                   (__attribute__((address_space(3))) void*)l, 16, 0, 0);
}

// ---------------- fused cast: all 5 inputs -> contiguous bf16 ws ----------------
#define CAST_TOTAL 3145728

__global__ __launch_bounds__(256)
void cast_all(const float* __restrict__ x, const float* __restrict__ x2,
              const float* __restrict__ wq, const float* __restrict__ wa,
              const float* __restrict__ wkv, unsigned short* __restrict__ out)
{
  for (int i = blockIdx.x*256 + threadIdx.x; i < CAST_TOTAL; i += gridDim.x*256){
    const float* src; int off;
    if      (i < 1048576){ src = x;   off = i; }
    else if (i < 2097152){ src = x2;  off = i - 1048576; }
    else if (i < 2359296){ src = wq;  off = i - 2097152; }
    else if (i < 2621440){ src = wa;  off = i - 2359296; }
    else                 { src = wkv; off = i - 2621440; }
    float4 v = ((const float4*)src)[off];
    ushort4 o;
    o.x = f2bf(v.x); o.y = f2bf(v.y); o.z = f2bf(v.z); o.w = f2bf(v.w);
    ((ushort4*)out)[i] = o;
  }
}

// ---------------- merged GEMM: all three projections in one dispatch ----------------
#define GK 1024

__global__ __launch_bounds__(256)
void gemm_all(const unsigned short* __restrict__ xb,  const unsigned short* __restrict__ x2b,
              const unsigned short* __restrict__ Wqb, const unsigned short* __restrict__ Wab,
              const unsigned short* __restrict__ Wkvb,
              unsigned short* __restrict__ Qw, unsigned short* __restrict__ Aw,
              unsigned short* __restrict__ Kw, unsigned short* __restrict__ Vwt)
{
  __shared__ unsigned short Ald[128*64];
  __shared__ unsigned short Bld[128*64];
  const int tid  = threadIdx.x;
  const int lane = tid & 63;
  const int wid  = tid >> 6;
  const int l15 = lane & 15, l4 = lane >> 4;
  const int wm = wid >> 1, wn = wid & 1;

  const int bid = blockIdx.x;
  const unsigned short *Abuf, *Bbuf;
  int mbase, nbase, isA;
  if (bid < 768){
    int nb = bid % 24, mb = bid / 24;
    nbase = nb*128; mbase = mb*128; isA = 0;
    Abuf = xb;
    Bbuf = (nbase < 1024) ? (Wqb + (size_t)nbase*GK) : (Wkvb + (size_t)(nbase-1024)*GK);
  } else {
    int b2 = bid - 768;
    int nb = b2 & 7, mb = b2 >> 3;
    nbase = nb*128; mbase = mb*128; isA = 1;
    Abuf = x2b;
    Bbuf = Wab + (size_t)nbase*GK;
  }

  const int srow = wid*32 + (lane >> 3);
  const int scol = (lane & 7)*8;
  const unsigned short* gA = Abuf + (size_t)(mbase + srow)*GK + scol;
  const unsigned short* gB = Bbuf + (size_t)srow*GK + scol;
  unsigned short* lA = Ald + (wid*32)*64;
  unsigned short* lB = Bld + (wid*32)*64;

  f32x4 acc[4][4];
  #pragma unroll
  for (int i=0;i<4;i++)
    #pragma unroll
    for(int j=0;j<4;j++) acc[i][j] = (f32x4){0.f,0.f,0.f,0.f};

  for (int kt = 0; kt < GK; kt += 64){
    __syncthreads();
    #pragma unroll
    for (int i=0;i<4;++i){
      gl_lds16(gA + (size_t)(i*8)*GK + kt, lA + i*8*64);
      gl_lds16(gB + (size_t)(i*8)*GK + kt, lB + i*8*64);
    }
    __syncthreads();
    #pragma unroll
    for (int kc = 0; kc < 2; ++kc){
      short8 af[4], bf[4];
      #pragma unroll
      for (int mt=0; mt<4; ++mt)
        af[mt] = *(const short8*)(Ald + (wm*64 + mt*16 + l15)*64 + kc*32 + l4*8);
      #pragma unroll
      for (int nt=0; nt<4; ++nt)
        bf[nt] = *(const short8*)(Bld + (wn*64 + nt*16 + l15)*64 + kc*32 + l4*8);
      #pragma unroll
      for (int mt=0; mt<4; ++mt)
        #pragma unroll
        for (int nt=0; nt<4; ++nt)
          acc[mt][nt] = __builtin_amdgcn_mfma_f32_16x16x32_bf16(af[mt], bf[nt], acc[mt][nt], 0,0,0);
    }
  }

  const float scale = isA ? SCLOG2 : 1.0f;
  #pragma unroll
  for (int mt=0; mt<4; ++mt){
    int mrow = mbase + wm*64 + mt*16 + l4*4;
    int b = mrow >> 11, nblk = mrow & 2047;
    #pragma unroll
    for (int nt=0; nt<4; ++nt){
      int col = nbase + wn*64 + nt*16 + l15;
      if (isA){
        int h = col >> 6, d = col & 63;
        #pragma unroll
        for (int r=0; r<4; ++r)
          Aw[((size_t)((b*HEADS + h)*SEQ + nblk + r))*HDIM + d] = f2bf(acc[mt][nt][r] * scale);
      } else if (col < 1024){
        int h = col >> 6, d = col & 63;
        #pragma unroll
        for (int r=0; r<4; ++r)
          Qw[((size_t)((b*HEADS + h)*SEQ + nblk + r))*HDIM + d] = f2bf(acc[mt][nt][r]);
      } else if (col < 2048){
        int c2 = col - 1024, h = c2 >> 6, d = c2 & 63;
        #pragma unroll
        for (int r=0; r<4; ++r)
          Kw[((size_t)((b*HEADS + h)*SEQ + nblk + r))*HDIM + d] = f2bf(acc[mt][nt][r]);
      } else {
        int c2 = col - 2048, h = c2 >> 6, d = c2 & 63;
        ushort4 pk;
        pk.x = f2bf(acc[mt][nt][0]);
        pk.y = f2bf(acc[mt][nt][1]);
        pk.z = f2bf(acc[mt][nt][2]);
        pk.w = f2bf(acc[mt][nt][3]);
        *(ushort4*)(Vwt + ((size_t)((b*HEADS + h)*HDIM + d))*SEQ + nblk) = pk;
      }
    }
  }
}

// ---------------- fused flash attention, swapped-operand 32x32, in-block KV split ----------
// (R8-proven structure + T5 setprio + slim vmcnt-only K-loop barrier)
// Q row-major [bh][q][d]; K row-major [bh][key][d]; V pre-transposed [bh][d][key]
// 8 waves: qw = wid&3 (32 q-rows each), kvh = wid>>2 (keys kvh*1024 .. +1024)
// mode 0: writes Y^T [bh][d][q] bf16. mode 1: writes fp32 out[b][q][h*64+d].
#define KT2 64
#define NTH 16     // tiles per kv half

__global__ __launch_bounds__(512)
void attn_pass(const unsigned short* __restrict__ Qb,
               const unsigned short* __restrict__ Kb,
               const unsigned short* __restrict__ Vtb,
               unsigned short* __restrict__ ytb,
               float* __restrict__ outf,
               int mode)
{
  // staging: [kvh][buf][16 frags * 512 shorts] = 64 KB; merge Of[128][68] f32 + Os overlay
  __shared__ __align__(16) char SHRAW[65536];
  unsigned short* SH = (unsigned short*)SHRAW;
  const int tid = threadIdx.x, lane = tid & 63, wid = tid >> 6;  // 8 waves
  const int l31 = lane & 31, l5 = lane >> 5;
  const int qw = wid & 3, kvh = wid >> 2;

  // XCD-aware decode: 4 bh per XCD, all 16 q-blocks of a bh on one XCD
  const int bid = blockIdx.x;
  const int cx = bid & 7, j = bid >> 3;
  const int bh = cx*4 + (j >> 4);
  const int qb = j & 15;
  const int q0 = qb*128 + qw*32;               // this wave's 32 q-rows
  const size_t base = (size_t)bh * SEQ * HDIM;

  // Q^T B-fragments (col q = l31, k-rows d = db*16 + l5*8 ..+8)
  short8 qf[4];
  #pragma unroll
  for (int db=0; db<4; ++db)
    qf[db] = *(const short8*)(Qb + base + (size_t)(q0 + l31)*HDIM + db*16 + l5*8);

  // staging duty within kv-group: qw 0,1 -> K frags, qw 2,3 -> V frags
  const unsigned short* gsrc[4];
  int ldst[4];
  int sstep;
  const int grpoff = kvh * 16384;
  if (qw < 2){
    #pragma unroll
    for (int f=0; f<4; ++f){
      gsrc[f] = Kb + base + (size_t)(kvh*1024 + qw*32 + l31)*HDIM + f*16 + l5*8;
      ldst[f] = grpoff + (qw*4 + f)*512;
    }
    sstep = KT2*HDIM;
  } else {
    const int db2 = qw - 2;
    #pragma unroll
    for (int f=0; f<4; ++f){
      gsrc[f] = Vtb + base + (size_t)(db2*32 + l31)*SEQ + kvh*1024 + f*16 + l5*8;
      ldst[f] = grpoff + 4096 + (db2*4 + f)*512;
    }
    sstep = KT2;
  }

  f32x16 oo0, oo1, ssum;
  #pragma unroll
  for (int r=0;r<16;++r){ oo0[r]=0.f; oo1[r]=0.f; ssum[r]=0.f; }
  short8 ones;
  #pragma unroll
  for (int jj=0;jj<8;++jj) ones[jj] = (short)0x3F80;

  #pragma unroll
  for (int f=0; f<4; ++f)
    gl_lds16(gsrc[f], SH + ldst[f]);
  asm volatile("s_waitcnt vmcnt(0)" ::: "memory");
  __builtin_amdgcn_s_barrier();
  __builtin_amdgcn_sched_barrier(0);

  for (int t = 0; t < NTH; ++t){
    const int cur = t & 1;
    if (t+1 < NTH){
      const int pbuf = ((t+1) & 1) * 8192;
      #pragma unroll
      for (int f=0; f<4; ++f)
        gl_lds16(gsrc[f] + (size_t)(t+1)*sstep, SH + ldst[f] + pbuf);
    }
    const unsigned short* Kc = SH + grpoff + cur*8192;
    const unsigned short* Vc = Kc + 4096;

    // S^T = K * Q^T : lane = col q0+l31, rows key = kb*32 + (r&3)+8*(r>>2)+4*l5
    float p[32];
    #pragma unroll
    for (int kb=0; kb<2; ++kb){
      f32x16 sacc;
      #pragma unroll
      for (int r=0;r<16;++r) sacc[r]=0.f;
      __builtin_amdgcn_s_setprio(1);
      #pragma unroll
      for (int db=0; db<4; ++db){
        short8 kfr = *(const short8*)(Kc + (kb*4+db)*512 + lane*8);
        sacc = __builtin_amdgcn_mfma_f32_32x32x16_bf16(kfr, qf[db], sacc, 0,0,0);
      }
      __builtin_amdgcn_s_setprio(0);
      #pragma unroll
      for (int r=0;r<16;++r)
        p[kb*16+r] = __builtin_amdgcn_exp2f(sacc[r]);  // scale pre-folded into A projection
    }

    // build P^T B-frags in registers; PV + ones-MFMA rowsum
    #pragma unroll
    for (int kb2=0; kb2<4; ++kb2){
      const int pb = (kb2>>1)*16 + (kb2&1)*8;
      int a0 = cvtpk(p[pb+0], p[pb+1]);
      int b0 = cvtpk(p[pb+4], p[pb+5]);
      int a1 = cvtpk(p[pb+2], p[pb+3]);
      int b1 = cvtpk(p[pb+6], p[pb+7]);
      swap32(a0, b0);
      swap32(a1, b1);
      i32x4 pav; pav[0]=a0; pav[1]=a1; pav[2]=b0; pav[3]=b1;
      short8 paf = *(short8*)&pav;
      __builtin_amdgcn_s_setprio(1);
      ssum = __builtin_amdgcn_mfma_f32_32x32x16_bf16(ones, paf, ssum, 0,0,0);
      short8 v0 = *(const short8*)(Vc + (0*4+kb2)*512 + lane*8);
      oo0 = __builtin_amdgcn_mfma_f32_32x32x16_bf16(v0, paf, oo0, 0,0,0);
      short8 v1 = *(const short8*)(Vc + (1*4+kb2)*512 + lane*8);
      oo1 = __builtin_amdgcn_mfma_f32_32x32x16_bf16(v1, paf, oo1, 0,0,0);
      __builtin_amdgcn_s_setprio(0);
    }

    // slim barrier: drain only the staging loads (ds_reads already consumed above)
    asm volatile("s_waitcnt vmcnt(0)" ::: "memory");
    __builtin_amdgcn_s_barrier();
    __builtin_amdgcn_sched_barrier(0);
  }

  // ---- in-block merge of the two kv halves ----
  float* Of  = (float*)SHRAW;                 // [128][68]
  float* Os1 = (float*)(SHRAW + 128*68*4);    // [128]
  const int ql = qw*32 + l31;

  if (kvh == 1){
    #pragma unroll
    for (int g=0; g<4; ++g){
      f32x4 w0, w1;
      #pragma unroll
      for (int r=0;r<4;++r){ w0[r] = oo0[g*4+r]; w1[r] = oo1[g*4+r]; }
      int d0 = 8*g + 4*l5;
      *(f32x4*)(Of + ql*68 + d0)      = w0;
      *(f32x4*)(Of + ql*68 + d0 + 32) = w1;
    }
    Os1[ql] = ssum[0];
  }
  __syncthreads();

  if (kvh == 0){
    const float rinv = 1.0f / (ssum[0] + Os1[ql]);
    if (mode == 0){
      #pragma unroll
      for (int r=0;r<16;++r){
        int d0 = (r&3) + 8*(r>>2) + 4*l5;
        float f0 = (oo0[r] + Of[ql*68 + d0])      * rinv;
        float f1 = (oo1[r] + Of[ql*68 + d0 + 32]) * rinv;
        ytb[base + (size_t)(d0)*SEQ + q0 + l31]    = f2bf(f0);
        ytb[base + (size_t)(d0+32)*SEQ + q0 + l31] = f2bf(f1);
      }
    } else {
      #pragma unroll
      for (int g=0; g<4; ++g){
        int d0 = 8*g + 4*l5;
        f32x4 w0 = *(const f32x4*)(Of + ql*68 + d0);
        f32x4 w1 = *(const f32x4*)(Of + ql*68 + d0 + 32);
        #pragma unroll
        for (int r=0;r<4;++r){ w0[r] = (w0[r]+oo0[g*4+r])*rinv; w1[r] = (w1[r]+oo1[g*4+r])*rinv; }
        *(f32x4*)(Of + ql*68 + d0)      = w0;
        *(f32x4*)(Of + ql*68 + d0 + 32) = w1;
      }
    }
  }

  if (mode == 1){
    __syncthreads();
    const int b = bh >> 4, h = bh & 15;
    const int qr = tid >> 2, dh = (tid & 3)*16;
    const float* src = Of + qr*68 + dh;
    float* drow = outf + ((size_t)(b*SEQ + qb*128 + qr))*DIM + h*HDIM + dh;
    #pragma unroll
    for (int k2=0;k2<4;++k2)
      *(float4*)(drow + k2*4) = *(const float4*)(src + k2*4);
  }
}

extern "C" void kernel_launch(void* const* d_in, const int* in_sizes, int n_in,
                              void* d_out, int out_size, void* d_ws, size_t ws_size,
                              hipStream_t stream) {
  const float* x   = (const float*)d_in[0];
  const float* x2  = (const float*)d_in[1];
  const float* Wq  = (const float*)d_in[2];
  const float* Wa  = (const float*)d_in[3];
  const float* Wkv = (const float*)d_in[4];
  float* out = (float*)d_out;

  unsigned short* ws = (unsigned short*)d_ws;
  unsigned short* xb   = ws;                      // 4096*1024
  unsigned short* x2b  = xb   + 4096*1024;
  unsigned short* Wqb  = x2b  + 4096*1024;        // 1024*1024
  unsigned short* Wab  = Wqb  + 1024*1024;
  unsigned short* Wkvb = Wab  + 1024*1024;        // 2048*1024
  unsigned short* Qw   = Wkvb + 2048*1024;        // BHND = 4194304 each
  unsigned short* Aw   = Qw   + 4194304;
  unsigned short* Kw   = Aw   + 4194304;
  unsigned short* Vwt  = Kw   + 4194304;          // V^T [bh][d][n] (direct from gemm)
  unsigned short* Ywt  = xb;                      // Y^T [bh][d][n] (xb dead after gemm)

  cast_all<<<dim3(3072), dim3(256), 0, stream>>>(x, x2, Wq, Wa, Wkv, ws);

  gemm_all<<<dim3(1024), dim3(256), 0, stream>>>(xb, x2b, Wqb, Wab, Wkvb, Qw, Aw, Kw, Vwt);

  // pass 1: Y^T = (softmax(A k^T s) v)^T  -- written directly transposed
  attn_pass<<<dim3(512), dim3(512), 0, stream>>>(Aw, Kw, Vwt, Ywt, nullptr, 0);

  // pass 2: out = softmax(q A^T s) Y
  attn_pass<<<dim3(512), dim3(512), 0, stream>>>(Qw, Aw, Ywt, nullptr, out, 1);
}

// Round 11
// 156.752 us; speedup vs baseline: 12.6025x; 1.0054x over previous
//
#include <hip/hip_runtime.h>

#define DIM 1024
#define HEADS 16
#define HDIM 64
#define SEQ 2048
// 0.125 * log2(e) — folded into A's projection epilogue
#define SCLOG2 0.18033688011112042f

typedef __attribute__((ext_vector_type(8))) short short8;
typedef __attribute__((ext_vector_type(4))) float f32x4;
typedef __attribute__((ext_vector_type(16))) float f32x16;
typedef __attribute__((ext_vector_type(4))) int i32x4;

static __device__ __forceinline__ unsigned short f2bf(float f){
  union { float f; unsigned int u; } v; v.f = f;
  unsigned int r = v.u + 0x7fffu + ((v.u >> 16) & 1u);
  return (unsigned short)(r >> 16);
}

static __device__ __forceinline__ int cvtpk(float lo, float hi){
  int r;
  asm("v_cvt_pk_bf16_f32 %0, %1, %2" : "=v"(r) : "v"(lo), "v"(hi));
  return r;
}
static __device__ __forceinline__ void swap32(int& a, int& b){
  asm("v_permlane32_swap_b32 %0, %1" : "+v"(a), "+v"(b));
}

__device__ __forceinline__ void gl_lds16(const unsigned short* g, unsigned short* l){
  __builtin_amdgcn_global_load_lds((const __attribute__((address_space(1))) void*)g,
                                   (__attribute__((address_space(3))) void*)l, 16, 0, 0);
}

// ---------------- fused cast: all 5 inputs -> contiguous bf16 ws ----------------
#define CAST_TOTAL 3145728

__global__ __launch_bounds__(256)
void cast_all(const float* __restrict__ x, const float* __restrict__ x2,
              const float* __restrict__ wq, const float* __restrict__ wa,
              const float* __restrict__ wkv, unsigned short* __restrict__ out)
{
  for (int i = blockIdx.x*256 + threadIdx.x; i < CAST_TOTAL; i += gridDim.x*256){
    const float* src; int off;
    if      (i < 1048576){ src = x;   off = i; }
    else if (i < 2097152){ src = x2;  off = i - 1048576; }
    else if (i < 2359296){ src = wq;  off = i - 2097152; }
    else if (i < 2621440){ src = wa;  off = i - 2359296; }
    else                 { src = wkv; off = i - 2621440; }
    float4 v = ((const float4*)src)[off];
    ushort4 o;
    o.x = f2bf(v.x); o.y = f2bf(v.y); o.z = f2bf(v.z); o.w = f2bf(v.w);
    ((ushort4*)out)[i] = o;
  }
}

// ---------------- merged GEMM: all three projections, double-buffered ----------------
// blocks 0..767:   x  @ [Wq|Wkv]^T  (N=3072): cols 0-1023 -> Q, 1024-2047 -> K, 2048-3071 -> V^T
// blocks 768..1023: x2 @ Wa^T       (N=1024): -> A (scaled by SCLOG2)
// XCD-stripe decode: each XCD owns 4 disjoint mb panels; weight tile reused by
// 4 consecutive blocks within the XCD.
// Q/K/A blocks: swapped-operand MFMA -> lane holds 4 consecutive d -> ushort4 stores.
#define GK 1024

__global__ __launch_bounds__(256)
void gemm_all(const unsigned short* __restrict__ xb,  const unsigned short* __restrict__ x2b,
              const unsigned short* __restrict__ Wqb, const unsigned short* __restrict__ Wab,
              const unsigned short* __restrict__ Wkvb,
              unsigned short* __restrict__ Qw, unsigned short* __restrict__ Aw,
              unsigned short* __restrict__ Kw, unsigned short* __restrict__ Vwt)
{
  __shared__ unsigned short Ald[2][128*64];   // 32 KB
  __shared__ unsigned short Bld[2][128*64];   // 32 KB
  const int tid  = threadIdx.x;
  const int lane = tid & 63;
  const int wid  = tid >> 6;
  const int l15 = lane & 15, l4 = lane >> 4;
  const int wm = wid >> 1, wn = wid & 1;

  const int bid = blockIdx.x;
  const unsigned short *Abuf, *Bbuf;
  int mbase, nbase, isA;
  if (bid < 768){
    int xcd = bid & 7, s = bid >> 3;       // s 0..95
    int mb = xcd*4 + (s & 3);              // 0..31, disjoint stripes per XCD
    int nb = s >> 2;                       // 0..23
    nbase = nb*128; mbase = mb*128; isA = 0;
    Abuf = xb;
    Bbuf = (nbase < 1024) ? (Wqb + (size_t)nbase*GK) : (Wkvb + (size_t)(nbase-1024)*GK);
  } else {
    int b2 = bid - 768;                    // 0..255
    int xcd = b2 & 7, s = b2 >> 3;         // s 0..31
    int mb = xcd*4 + (s & 3);
    int nb = s >> 2;                       // 0..7
    nbase = nb*128; mbase = mb*128; isA = 1;
    Abuf = x2b;
    Bbuf = Wab + (size_t)nbase*GK;
  }
  const bool isV = (!isA) && (nbase >= 2048);

  const int srow = wid*32 + (lane >> 3);
  const int scol = (lane & 7)*8;
  const unsigned short* gA = Abuf + (size_t)(mbase + srow)*GK + scol;
  const unsigned short* gB = Bbuf + (size_t)srow*GK + scol;

  f32x4 acc[4][4];
  #pragma unroll
  for (int i=0;i<4;i++)
    #pragma unroll
    for(int j=0;j<4;j++) acc[i][j] = (f32x4){0.f,0.f,0.f,0.f};

  // prologue: stage k-tile 0 into buf 0
  #pragma unroll
  for (int i=0;i<4;++i){
    gl_lds16(gA + (size_t)(i*8)*GK, &Ald[0][(wid*32 + i*8)*64]);
    gl_lds16(gB + (size_t)(i*8)*GK, &Bld[0][(wid*32 + i*8)*64]);
  }
  asm volatile("s_waitcnt vmcnt(0)" ::: "memory");
  __builtin_amdgcn_s_barrier();
  __builtin_amdgcn_sched_barrier(0);

  for (int t = 0; t < 16; ++t){
    const int cur = t & 1;
    if (t+1 < 16){
      const int nxt = cur ^ 1;
      const int kt = (t+1)*64;
      #pragma unroll
      for (int i=0;i<4;++i){
        gl_lds16(gA + (size_t)(i*8)*GK + kt, &Ald[nxt][(wid*32 + i*8)*64]);
        gl_lds16(gB + (size_t)(i*8)*GK + kt, &Bld[nxt][(wid*32 + i*8)*64]);
      }
    }
    #pragma unroll
    for (int kc = 0; kc < 2; ++kc){
      short8 af[4], bf[4];
      #pragma unroll
      for (int mt=0; mt<4; ++mt)
        af[mt] = *(const short8*)(&Ald[cur][(wm*64 + mt*16 + l15)*64 + kc*32 + l4*8]);
      #pragma unroll
      for (int nt=0; nt<4; ++nt)
        bf[nt] = *(const short8*)(&Bld[cur][(wn*64 + nt*16 + l15)*64 + kc*32 + l4*8]);
      __builtin_amdgcn_s_setprio(1);
      if (isV){
        #pragma unroll
        for (int mt=0; mt<4; ++mt)
          #pragma unroll
          for (int nt=0; nt<4; ++nt)
            acc[mt][nt] = __builtin_amdgcn_mfma_f32_16x16x32_bf16(af[mt], bf[nt], acc[mt][nt], 0,0,0);
      } else {
        // swapped: rows = weight col (d), cols = token -> packed d stores
        #pragma unroll
        for (int mt=0; mt<4; ++mt)
          #pragma unroll
          for (int nt=0; nt<4; ++nt)
            acc[mt][nt] = __builtin_amdgcn_mfma_f32_16x16x32_bf16(bf[nt], af[mt], acc[mt][nt], 0,0,0);
      }
      __builtin_amdgcn_s_setprio(0);
    }
    asm volatile("s_waitcnt vmcnt(0)" ::: "memory");
    __builtin_amdgcn_s_barrier();
    __builtin_amdgcn_sched_barrier(0);
  }

  if (!isV){
    // acc[mt][nt]: col(l15)=token within mt-tile, rows(l4*4+r)=output col within nt-tile
    unsigned short* dst = isA ? Aw : (nbase < 1024 ? Qw : Kw);
    const int coff = (!isA && nbase >= 1024) ? 1024 : 0;
    const float scale = isA ? SCLOG2 : 1.0f;
    #pragma unroll
    for (int mt=0; mt<4; ++mt){
      int token = mbase + wm*64 + mt*16 + l15;
      int b = token >> 11, n = token & 2047;
      #pragma unroll
      for (int nt=0; nt<4; ++nt){
        int colb = nbase - coff + wn*64 + nt*16 + l4*4;
        int h = colb >> 6, d = colb & 63;
        ushort4 pk;
        pk.x = f2bf(acc[mt][nt][0] * scale);
        pk.y = f2bf(acc[mt][nt][1] * scale);
        pk.z = f2bf(acc[mt][nt][2] * scale);
        pk.w = f2bf(acc[mt][nt][3] * scale);
        *(ushort4*)(dst + ((size_t)((b*HEADS + h)*SEQ + n))*HDIM + d) = pk;
      }
    }
  } else {
    // V: rows(l4*4+r)=token, col(l15)=output col -> packed token stores into V^T
    #pragma unroll
    for (int mt=0; mt<4; ++mt){
      int mrow = mbase + wm*64 + mt*16 + l4*4;
      int b = mrow >> 11, nblk = mrow & 2047;
      #pragma unroll
      for (int nt=0; nt<4; ++nt){
        int col = nbase + wn*64 + nt*16 + l15;
        int c2 = col - 2048, h = c2 >> 6, d = c2 & 63;
        ushort4 pk;
        pk.x = f2bf(acc[mt][nt][0]);
        pk.y = f2bf(acc[mt][nt][1]);
        pk.z = f2bf(acc[mt][nt][2]);
        pk.w = f2bf(acc[mt][nt][3]);
        *(ushort4*)(Vwt + ((size_t)((b*HEADS + h)*HDIM + d))*SEQ + nblk) = pk;
      }
    }
  }
}

// ---------------- fused flash attention, swapped-operand 32x32, in-block KV split ----------
// (R10-proven: T5 setprio + slim vmcnt-only K-loop barrier) — UNCHANGED
#define KT2 64
#define NTH 16     // tiles per kv half

__global__ __launch_bounds__(512)
void attn_pass(const unsigned short* __restrict__ Qb,
               const unsigned short* __restrict__ Kb,
               const unsigned short* __restrict__ Vtb,
               unsigned short* __restrict__ ytb,
               float* __restrict__ outf,
               int mode)
{
  __shared__ __align__(16) char SHRAW[65536];
  unsigned short* SH = (unsigned short*)SHRAW;
  const int tid = threadIdx.x, lane = tid & 63, wid = tid >> 6;  // 8 waves
  const int l31 = lane & 31, l5 = lane >> 5;
  const int qw = wid & 3, kvh = wid >> 2;

  const int bid = blockIdx.x;
  const int cx = bid & 7, j = bid >> 3;
  const int bh = cx*4 + (j >> 4);
  const int qb = j & 15;
  const int q0 = qb*128 + qw*32;
  const size_t base = (size_t)bh * SEQ * HDIM;

  short8 qf[4];
  #pragma unroll
  for (int db=0; db<4; ++db)
    qf[db] = *(const short8*)(Qb + base + (size_t)(q0 + l31)*HDIM + db*16 + l5*8);

  const unsigned short* gsrc[4];
  int ldst[4];
  int sstep;
  const int grpoff = kvh * 16384;
  if (qw < 2){
    #pragma unroll
    for (int f=0; f<4; ++f){
      gsrc[f] = Kb + base + (size_t)(kvh*1024 + qw*32 + l31)*HDIM + f*16 + l5*8;
      ldst[f] = grpoff + (qw*4 + f)*512;
    }
    sstep = KT2*HDIM;
  } else {
    const int db2 = qw - 2;
    #pragma unroll
    for (int f=0; f<4; ++f){
      gsrc[f] = Vtb + base + (size_t)(db2*32 + l31)*SEQ + kvh*1024 + f*16 + l5*8;
      ldst[f] = grpoff + 4096 + (db2*4 + f)*512;
    }
    sstep = KT2;
  }

  f32x16 oo0, oo1, ssum;
  #pragma unroll
  for (int r=0;r<16;++r){ oo0[r]=0.f; oo1[r]=0.f; ssum[r]=0.f; }
  short8 ones;
  #pragma unroll
  for (int jj=0;jj<8;++jj) ones[jj] = (short)0x3F80;

  #pragma unroll
  for (int f=0; f<4; ++f)
    gl_lds16(gsrc[f], SH + ldst[f]);
  asm volatile("s_waitcnt vmcnt(0)" ::: "memory");
  __builtin_amdgcn_s_barrier();
  __builtin_amdgcn_sched_barrier(0);

  for (int t = 0; t < NTH; ++t){
    const int cur = t & 1;
    if (t+1 < NTH){
      const int pbuf = ((t+1) & 1) * 8192;
      #pragma unroll
      for (int f=0; f<4; ++f)
        gl_lds16(gsrc[f] + (size_t)(t+1)*sstep, SH + ldst[f] + pbuf);
    }
    const unsigned short* Kc = SH + grpoff + cur*8192;
    const unsigned short* Vc = Kc + 4096;

    float p[32];
    #pragma unroll
    for (int kb=0; kb<2; ++kb){
      f32x16 sacc;
      #pragma unroll
      for (int r=0;r<16;++r) sacc[r]=0.f;
      __builtin_amdgcn_s_setprio(1);
      #pragma unroll
      for (int db=0; db<4; ++db){
        short8 kfr = *(const short8*)(Kc + (kb*4+db)*512 + lane*8);
        sacc = __builtin_amdgcn_mfma_f32_32x32x16_bf16(kfr, qf[db], sacc, 0,0,0);
      }
      __builtin_amdgcn_s_setprio(0);
      #pragma unroll
      for (int r=0;r<16;++r)
        p[kb*16+r] = __builtin_amdgcn_exp2f(sacc[r]);
    }

    #pragma unroll
    for (int kb2=0; kb2<4; ++kb2){
      const int pb = (kb2>>1)*16 + (kb2&1)*8;
      int a0 = cvtpk(p[pb+0], p[pb+1]);
      int b0 = cvtpk(p[pb+4], p[pb+5]);
      int a1 = cvtpk(p[pb+2], p[pb+3]);
      int b1 = cvtpk(p[pb+6], p[pb+7]);
      swap32(a0, b0);
      swap32(a1, b1);
      i32x4 pav; pav[0]=a0; pav[1]=a1; pav[2]=b0; pav[3]=b1;
      short8 paf = *(short8*)&pav;
      __builtin_amdgcn_s_setprio(1);
      ssum = __builtin_amdgcn_mfma_f32_32x32x16_bf16(ones, paf, ssum, 0,0,0);
      short8 v0 = *(const short8*)(Vc + (0*4+kb2)*512 + lane*8);
      oo0 = __builtin_amdgcn_mfma_f32_32x32x16_bf16(v0, paf, oo0, 0,0,0);
      short8 v1 = *(const short8*)(Vc + (1*4+kb2)*512 + lane*8);
      oo1 = __builtin_amdgcn_mfma_f32_32x32x16_bf16(v1, paf, oo1, 0,0,0);
      __builtin_amdgcn_s_setprio(0);
    }

    asm volatile("s_waitcnt vmcnt(0)" ::: "memory");
    __builtin_amdgcn_s_barrier();
    __builtin_amdgcn_sched_barrier(0);
  }

  float* Of  = (float*)SHRAW;                 // [128][68]
  float* Os1 = (float*)(SHRAW + 128*68*4);    // [128]
  const int ql = qw*32 + l31;

  if (kvh == 1){
    #pragma unroll
    for (int g=0; g<4; ++g){
      f32x4 w0, w1;
      #pragma unroll
      for (int r=0;r<4;++r){ w0[r] = oo0[g*4+r]; w1[r] = oo1[g*4+r]; }
      int d0 = 8*g + 4*l5;
      *(f32x4*)(Of + ql*68 + d0)      = w0;
      *(f32x4*)(Of + ql*68 + d0 + 32) = w1;
    }
    Os1[ql] = ssum[0];
  }
  __syncthreads();

  if (kvh == 0){
    const float rinv = 1.0f / (ssum[0] + Os1[ql]);
    if (mode == 0){
      #pragma unroll
      for (int r=0;r<16;++r){
        int d0 = (r&3) + 8*(r>>2) + 4*l5;
        float f0 = (oo0[r] + Of[ql*68 + d0])      * rinv;
        float f1 = (oo1[r] + Of[ql*68 + d0 + 32]) * rinv;
        ytb[base + (size_t)(d0)*SEQ + q0 + l31]    = f2bf(f0);
        ytb[base + (size_t)(d0+32)*SEQ + q0 + l31] = f2bf(f1);
      }
    } else {
      #pragma unroll
      for (int g=0; g<4; ++g){
        int d0 = 8*g + 4*l5;
        f32x4 w0 = *(const f32x4*)(Of + ql*68 + d0);
        f32x4 w1 = *(const f32x4*)(Of + ql*68 + d0 + 32);
        #pragma unroll
        for (int r=0;r<4;++r){ w0[r] = (w0[r]+oo0[g*4+r])*rinv; w1[r] = (w1[r]+oo1[g*4+r])*rinv; }
        *(f32x4*)(Of + ql*68 + d0)      = w0;
        *(f32x4*)(Of + ql*68 + d0 + 32) = w1;
      }
    }
  }

  if (mode == 1){
    __syncthreads();
    const int b = bh >> 4, h = bh & 15;
    const int qr = tid >> 2, dh = (tid & 3)*16;
    const float* src = Of + qr*68 + dh;
    float* drow = outf + ((size_t)(b*SEQ + qb*128 + qr))*DIM + h*HDIM + dh;
    #pragma unroll
    for (int k2=0;k2<4;++k2)
      *(float4*)(drow + k2*4) = *(const float4*)(src + k2*4);
  }
}

extern "C" void kernel_launch(void* const* d_in, const int* in_sizes, int n_in,
                              void* d_out, int out_size, void* d_ws, size_t ws_size,
                              hipStream_t stream) {
  const float* x   = (const float*)d_in[0];
  const float* x2  = (const float*)d_in[1];
  const float* Wq  = (const float*)d_in[2];
  const float* Wa  = (const float*)d_in[3];
  const float* Wkv = (const float*)d_in[4];
  float* out = (float*)d_out;

  unsigned short* ws = (unsigned short*)d_ws;
  unsigned short* xb   = ws;                      // 4096*1024
  unsigned short* x2b  = xb   + 4096*1024;
  unsigned short* Wqb  = x2b  + 4096*1024;        // 1024*1024
  unsigned short* Wab  = Wqb  + 1024*1024;
  unsigned short* Wkvb = Wab  + 1024*1024;        // 2048*1024
  unsigned short* Qw   = Wkvb + 2048*1024;        // BHND = 4194304 each
  unsigned short* Aw   = Qw   + 4194304;
  unsigned short* Kw   = Aw   + 4194304;
  unsigned short* Vwt  = Kw   + 4194304;          // V^T [bh][d][n] (direct from gemm)
  unsigned short* Ywt  = xb;                      // Y^T [bh][d][n] (xb dead after gemm)

  cast_all<<<dim3(3072), dim3(256), 0, stream>>>(x, x2, Wq, Wa, Wkv, ws);

  gemm_all<<<dim3(1024), dim3(256), 0, stream>>>(xb, x2b, Wqb, Wab, Wkvb, Qw, Aw, Kw, Vwt);

  // pass 1: Y^T = (softmax(A k^T s) v)^T  -- written directly transposed
  attn_pass<<<dim3(512), dim3(512), 0, stream>>>(Aw, Kw, Vwt, Ywt, nullptr, 0);

  // pass 2: out = softmax(q A^T s) Y
  attn_pass<<<dim3(512), dim3(512), 0, stream>>>(Qw, Aw, Ywt, nullptr, out, 1);
}

// Round 12
// 149.484 us; speedup vs baseline: 13.2153x; 1.0486x over previous
//
#include <hip/hip_runtime.h>

#define DIM 1024
#define HEADS 16
#define HDIM 64
#define SEQ 2048
// 0.125 * log2(e) — folded into A's projection epilogue
#define SCLOG2 0.18033688011112042f

typedef __attribute__((ext_vector_type(8))) short short8;
typedef __attribute__((ext_vector_type(4))) float f32x4;
typedef __attribute__((ext_vector_type(16))) float f32x16;
typedef __attribute__((ext_vector_type(4))) int i32x4;

static __device__ __forceinline__ unsigned short f2bf(float f){
  union { float f; unsigned int u; } v; v.f = f;
  unsigned int r = v.u + 0x7fffu + ((v.u >> 16) & 1u);
  return (unsigned short)(r >> 16);
}

static __device__ __forceinline__ int cvtpk(float lo, float hi){
  int r;
  asm("v_cvt_pk_bf16_f32 %0, %1, %2" : "=v"(r) : "v"(lo), "v"(hi));
  return r;
}
static __device__ __forceinline__ void swap32(int& a, int& b){
  asm("v_permlane32_swap_b32 %0, %1" : "+v"(a), "+v"(b));
}

__device__ __forceinline__ void gl_lds16(const unsigned short* g, unsigned short* l){
  __builtin_amdgcn_global_load_lds((const __attribute__((address_space(1))) void*)g,
                                   (__attribute__((address_space(3))) void*)l, 16, 0, 0);
}

// ---------------- fused cast: all 5 inputs -> contiguous bf16 ws ----------------
#define CAST_TOTAL 3145728

__global__ __launch_bounds__(256)
void cast_all(const float* __restrict__ x, const float* __restrict__ x2,
              const float* __restrict__ wq, const float* __restrict__ wa,
              const float* __restrict__ wkv, unsigned short* __restrict__ out)
{
  for (int i = blockIdx.x*256 + threadIdx.x; i < CAST_TOTAL; i += gridDim.x*256){
    const float* src; int off;
    if      (i < 1048576){ src = x;   off = i; }
    else if (i < 2097152){ src = x2;  off = i - 1048576; }
    else if (i < 2359296){ src = wq;  off = i - 2097152; }
    else if (i < 2621440){ src = wa;  off = i - 2359296; }
    else                 { src = wkv; off = i - 2621440; }
    float4 v = ((const float4*)src)[off];
    ushort4 o;
    o.x = f2bf(v.x); o.y = f2bf(v.y); o.z = f2bf(v.z); o.w = f2bf(v.w);
    ((ushort4*)out)[i] = o;
  }
}

// ---------------- merged GEMM: all three projections, double-buffered, XOR-swizzled LDS ----
// blocks 0..767:   x  @ [Wq|Wkv]^T  (N=3072): cols 0-1023 -> Q, 1024-2047 -> K, 2048-3071 -> V^T
// blocks 768..1023: x2 @ Wa^T       (N=1024): -> A (scaled by SCLOG2)
// LDS swizzle (both-sides, rule #21): logical chunk c of row r lives at slot c^(r&7).
//   write: global source pre-swizzled (scol = ((lane&7)^(lane>>3))*8), LDS dest linear.
//   read:  col = (kc*32 + l4*8) ^ ((l15&7)*8).
#define GK 1024

__global__ __launch_bounds__(256)
void gemm_all(const unsigned short* __restrict__ xb,  const unsigned short* __restrict__ x2b,
              const unsigned short* __restrict__ Wqb, const unsigned short* __restrict__ Wab,
              const unsigned short* __restrict__ Wkvb,
              unsigned short* __restrict__ Qw, unsigned short* __restrict__ Aw,
              unsigned short* __restrict__ Kw, unsigned short* __restrict__ Vwt)
{
  __shared__ unsigned short Ald[2][128*64];   // 32 KB
  __shared__ unsigned short Bld[2][128*64];   // 32 KB
  const int tid  = threadIdx.x;
  const int lane = tid & 63;
  const int wid  = tid >> 6;
  const int l15 = lane & 15, l4 = lane >> 4;
  const int wm = wid >> 1, wn = wid & 1;

  const int bid = blockIdx.x;
  const unsigned short *Abuf, *Bbuf;
  int mbase, nbase, isA;
  if (bid < 768){
    int xcd = bid & 7, s = bid >> 3;       // s 0..95
    int mb = xcd*4 + (s & 3);              // 0..31, disjoint stripes per XCD
    int nb = s >> 2;                       // 0..23
    nbase = nb*128; mbase = mb*128; isA = 0;
    Abuf = xb;
    Bbuf = (nbase < 1024) ? (Wqb + (size_t)nbase*GK) : (Wkvb + (size_t)(nbase-1024)*GK);
  } else {
    int b2 = bid - 768;                    // 0..255
    int xcd = b2 & 7, s = b2 >> 3;         // s 0..31
    int mb = xcd*4 + (s & 3);
    int nb = s >> 2;                       // 0..7
    nbase = nb*128; mbase = mb*128; isA = 1;
    Abuf = x2b;
    Bbuf = Wab + (size_t)nbase*GK;
  }
  const bool isV = (!isA) && (nbase >= 2048);

  const int srow = wid*32 + (lane >> 3);
  const int scol = ((lane & 7) ^ (lane >> 3)) * 8;   // pre-swizzled source column
  const unsigned short* gA = Abuf + (size_t)(mbase + srow)*GK + scol;
  const unsigned short* gB = Bbuf + (size_t)srow*GK + scol;

  // read-side swizzles (row&7 == l15&7 for all fragment rows)
  const int rsw = (l15 & 7) * 8;

  f32x4 acc[4][4];
  #pragma unroll
  for (int i=0;i<4;i++)
    #pragma unroll
    for(int j=0;j<4;j++) acc[i][j] = (f32x4){0.f,0.f,0.f,0.f};

  // prologue: stage k-tile 0 into buf 0
  #pragma unroll
  for (int i=0;i<4;++i){
    gl_lds16(gA + (size_t)(i*8)*GK, &Ald[0][(wid*32 + i*8)*64]);
    gl_lds16(gB + (size_t)(i*8)*GK, &Bld[0][(wid*32 + i*8)*64]);
  }
  asm volatile("s_waitcnt vmcnt(0)" ::: "memory");
  __builtin_amdgcn_s_barrier();
  __builtin_amdgcn_sched_barrier(0);

  for (int t = 0; t < 16; ++t){
    const int cur = t & 1;
    if (t+1 < 16){
      const int nxt = cur ^ 1;
      const int kt = (t+1)*64;
      #pragma unroll
      for (int i=0;i<4;++i){
        gl_lds16(gA + (size_t)(i*8)*GK + kt, &Ald[nxt][(wid*32 + i*8)*64]);
        gl_lds16(gB + (size_t)(i*8)*GK + kt, &Bld[nxt][(wid*32 + i*8)*64]);
      }
    }
    #pragma unroll
    for (int kc = 0; kc < 2; ++kc){
      short8 af[4], bf[4];
      #pragma unroll
      for (int mt=0; mt<4; ++mt)
        af[mt] = *(const short8*)(&Ald[cur][(wm*64 + mt*16 + l15)*64 + ((kc*32 + l4*8) ^ rsw)]);
      #pragma unroll
      for (int nt=0; nt<4; ++nt)
        bf[nt] = *(const short8*)(&Bld[cur][(wn*64 + nt*16 + l15)*64 + ((kc*32 + l4*8) ^ rsw)]);
      __builtin_amdgcn_s_setprio(1);
      if (isV){
        #pragma unroll
        for (int mt=0; mt<4; ++mt)
          #pragma unroll
          for (int nt=0; nt<4; ++nt)
            acc[mt][nt] = __builtin_amdgcn_mfma_f32_16x16x32_bf16(af[mt], bf[nt], acc[mt][nt], 0,0,0);
      } else {
        // swapped: rows = weight col (d), cols = token -> packed d stores
        #pragma unroll
        for (int mt=0; mt<4; ++mt)
          #pragma unroll
          for (int nt=0; nt<4; ++nt)
            acc[mt][nt] = __builtin_amdgcn_mfma_f32_16x16x32_bf16(bf[nt], af[mt], acc[mt][nt], 0,0,0);
      }
      __builtin_amdgcn_s_setprio(0);
    }
    asm volatile("s_waitcnt vmcnt(0)" ::: "memory");
    __builtin_amdgcn_s_barrier();
    __builtin_amdgcn_sched_barrier(0);
  }

  if (!isV){
    // acc[mt][nt]: col(l15)=token within mt-tile, rows(l4*4+r)=output col within nt-tile
    unsigned short* dst = isA ? Aw : (nbase < 1024 ? Qw : Kw);
    const int coff = (!isA && nbase >= 1024) ? 1024 : 0;
    const float scale = isA ? SCLOG2 : 1.0f;
    #pragma unroll
    for (int mt=0; mt<4; ++mt){
      int token = mbase + wm*64 + mt*16 + l15;
      int b = token >> 11, n = token & 2047;
      #pragma unroll
      for (int nt=0; nt<4; ++nt){
        int colb = nbase - coff + wn*64 + nt*16 + l4*4;
        int h = colb >> 6, d = colb & 63;
        ushort4 pk;
        pk.x = f2bf(acc[mt][nt][0] * scale);
        pk.y = f2bf(acc[mt][nt][1] * scale);
        pk.z = f2bf(acc[mt][nt][2] * scale);
        pk.w = f2bf(acc[mt][nt][3] * scale);
        *(ushort4*)(dst + ((size_t)((b*HEADS + h)*SEQ + n))*HDIM + d) = pk;
      }
    }
  } else {
    // V: rows(l4*4+r)=token, col(l15)=output col -> packed token stores into V^T
    #pragma unroll
    for (int mt=0; mt<4; ++mt){
      int mrow = mbase + wm*64 + mt*16 + l4*4;
      int b = mrow >> 11, nblk = mrow & 2047;
      #pragma unroll
      for (int nt=0; nt<4; ++nt){
        int col = nbase + wn*64 + nt*16 + l15;
        int c2 = col - 2048, h = c2 >> 6, d = c2 & 63;
        ushort4 pk;
        pk.x = f2bf(acc[mt][nt][0]);
        pk.y = f2bf(acc[mt][nt][1]);
        pk.z = f2bf(acc[mt][nt][2]);
        pk.w = f2bf(acc[mt][nt][3]);
        *(ushort4*)(Vwt + ((size_t)((b*HEADS + h)*HDIM + d))*SEQ + nblk) = pk;
      }
    }
  }
}

// ---------------- fused flash attention, swapped-operand 32x32, in-block KV split ----------
// (R10-proven: T5 setprio + slim vmcnt-only K-loop barrier) — UNCHANGED
#define KT2 64
#define NTH 16     // tiles per kv half

__global__ __launch_bounds__(512)
void attn_pass(const unsigned short* __restrict__ Qb,
               const unsigned short* __restrict__ Kb,
               const unsigned short* __restrict__ Vtb,
               unsigned short* __restrict__ ytb,
               float* __restrict__ outf,
               int mode)
{
  __shared__ __align__(16) char SHRAW[65536];
  unsigned short* SH = (unsigned short*)SHRAW;
  const int tid = threadIdx.x, lane = tid & 63, wid = tid >> 6;  // 8 waves
  const int l31 = lane & 31, l5 = lane >> 5;
  const int qw = wid & 3, kvh = wid >> 2;

  const int bid = blockIdx.x;
  const int cx = bid & 7, j = bid >> 3;
  const int bh = cx*4 + (j >> 4);
  const int qb = j & 15;
  const int q0 = qb*128 + qw*32;
  const size_t base = (size_t)bh * SEQ * HDIM;

  short8 qf[4];
  #pragma unroll
  for (int db=0; db<4; ++db)
    qf[db] = *(const short8*)(Qb + base + (size_t)(q0 + l31)*HDIM + db*16 + l5*8);

  const unsigned short* gsrc[4];
  int ldst[4];
  int sstep;
  const int grpoff = kvh * 16384;
  if (qw < 2){
    #pragma unroll
    for (int f=0; f<4; ++f){
      gsrc[f] = Kb + base + (size_t)(kvh*1024 + qw*32 + l31)*HDIM + f*16 + l5*8;
      ldst[f] = grpoff + (qw*4 + f)*512;
    }
    sstep = KT2*HDIM;
  } else {
    const int db2 = qw - 2;
    #pragma unroll
    for (int f=0; f<4; ++f){
      gsrc[f] = Vtb + base + (size_t)(db2*32 + l31)*SEQ + kvh*1024 + f*16 + l5*8;
      ldst[f] = grpoff + 4096 + (db2*4 + f)*512;
    }
    sstep = KT2;
  }

  f32x16 oo0, oo1, ssum;
  #pragma unroll
  for (int r=0;r<16;++r){ oo0[r]=0.f; oo1[r]=0.f; ssum[r]=0.f; }
  short8 ones;
  #pragma unroll
  for (int jj=0;jj<8;++jj) ones[jj] = (short)0x3F80;

  #pragma unroll
  for (int f=0; f<4; ++f)
    gl_lds16(gsrc[f], SH + ldst[f]);
  asm volatile("s_waitcnt vmcnt(0)" ::: "memory");
  __builtin_amdgcn_s_barrier();
  __builtin_amdgcn_sched_barrier(0);

  for (int t = 0; t < NTH; ++t){
    const int cur = t & 1;
    if (t+1 < NTH){
      const int pbuf = ((t+1) & 1) * 8192;
      #pragma unroll
      for (int f=0; f<4; ++f)
        gl_lds16(gsrc[f] + (size_t)(t+1)*sstep, SH + ldst[f] + pbuf);
    }
    const unsigned short* Kc = SH + grpoff + cur*8192;
    const unsigned short* Vc = Kc + 4096;

    float p[32];
    #pragma unroll
    for (int kb=0; kb<2; ++kb){
      f32x16 sacc;
      #pragma unroll
      for (int r=0;r<16;++r) sacc[r]=0.f;
      __builtin_amdgcn_s_setprio(1);
      #pragma unroll
      for (int db=0; db<4; ++db){
        short8 kfr = *(const short8*)(Kc + (kb*4+db)*512 + lane*8);
        sacc = __builtin_amdgcn_mfma_f32_32x32x16_bf16(kfr, qf[db], sacc, 0,0,0);
      }
      __builtin_amdgcn_s_setprio(0);
      #pragma unroll
      for (int r=0;r<16;++r)
        p[kb*16+r] = __builtin_amdgcn_exp2f(sacc[r]);
    }

    #pragma unroll
    for (int kb2=0; kb2<4; ++kb2){
      const int pb = (kb2>>1)*16 + (kb2&1)*8;
      int a0 = cvtpk(p[pb+0], p[pb+1]);
      int b0 = cvtpk(p[pb+4], p[pb+5]);
      int a1 = cvtpk(p[pb+2], p[pb+3]);
      int b1 = cvtpk(p[pb+6], p[pb+7]);
      swap32(a0, b0);
      swap32(a1, b1);
      i32x4 pav; pav[0]=a0; pav[1]=a1; pav[2]=b0; pav[3]=b1;
      short8 paf = *(short8*)&pav;
      __builtin_amdgcn_s_setprio(1);
      ssum = __builtin_amdgcn_mfma_f32_32x32x16_bf16(ones, paf, ssum, 0,0,0);
      short8 v0 = *(const short8*)(Vc + (0*4+kb2)*512 + lane*8);
      oo0 = __builtin_amdgcn_mfma_f32_32x32x16_bf16(v0, paf, oo0, 0,0,0);
      short8 v1 = *(const short8*)(Vc + (1*4+kb2)*512 + lane*8);
      oo1 = __builtin_amdgcn_mfma_f32_32x32x16_bf16(v1, paf, oo1, 0,0,0);
      __builtin_amdgcn_s_setprio(0);
    }

    asm volatile("s_waitcnt vmcnt(0)" ::: "memory");
    __builtin_amdgcn_s_barrier();
    __builtin_amdgcn_sched_barrier(0);
  }

  float* Of  = (float*)SHRAW;                 // [128][68]
  float* Os1 = (float*)(SHRAW + 128*68*4);    // [128]
  const int ql = qw*32 + l31;

  if (kvh == 1){
    #pragma unroll
    for (int g=0; g<4; ++g){
      f32x4 w0, w1;
      #pragma unroll
      for (int r=0;r<4;++r){ w0[r] = oo0[g*4+r]; w1[r] = oo1[g*4+r]; }
      int d0 = 8*g + 4*l5;
      *(f32x4*)(Of + ql*68 + d0)      = w0;
      *(f32x4*)(Of + ql*68 + d0 + 32) = w1;
    }
    Os1[ql] = ssum[0];
  }
  __syncthreads();

  if (kvh == 0){
    const float rinv = 1.0f / (ssum[0] + Os1[ql]);
    if (mode == 0){
      #pragma unroll
      for (int r=0;r<16;++r){
        int d0 = (r&3) + 8*(r>>2) + 4*l5;
        float f0 = (oo0[r] + Of[ql*68 + d0])      * rinv;
        float f1 = (oo1[r] + Of[ql*68 + d0 + 32]) * rinv;
        ytb[base + (size_t)(d0)*SEQ + q0 + l31]    = f2bf(f0);
        ytb[base + (size_t)(d0+32)*SEQ + q0 + l31] = f2bf(f1);
      }
    } else {
      #pragma unroll
      for (int g=0; g<4; ++g){
        int d0 = 8*g + 4*l5;
        f32x4 w0 = *(const f32x4*)(Of + ql*68 + d0);
        f32x4 w1 = *(const f32x4*)(Of + ql*68 + d0 + 32);
        #pragma unroll
        for (int r=0;r<4;++r){ w0[r] = (w0[r]+oo0[g*4+r])*rinv; w1[r] = (w1[r]+oo1[g*4+r])*rinv; }
        *(f32x4*)(Of + ql*68 + d0)      = w0;
        *(f32x4*)(Of + ql*68 + d0 + 32) = w1;
      }
    }
  }

  if (mode == 1){
    __syncthreads();
    const int b = bh >> 4, h = bh & 15;
    const int qr = tid >> 2, dh = (tid & 3)*16;
    const float* src = Of + qr*68 + dh;
    float* drow = outf + ((size_t)(b*SEQ + qb*128 + qr))*DIM + h*HDIM + dh;
    #pragma unroll
    for (int k2=0;k2<4;++k2)
      *(float4*)(drow + k2*4) = *(const float4*)(src + k2*4);
  }
}

extern "C" void kernel_launch(void* const* d_in, const int* in_sizes, int n_in,
                              void* d_out, int out_size, void* d_ws, size_t ws_size,
                              hipStream_t stream) {
  const float* x   = (const float*)d_in[0];
  const float* x2  = (const float*)d_in[1];
  const float* Wq  = (const float*)d_in[2];
  const float* Wa  = (const float*)d_in[3];
  const float* Wkv = (const float*)d_in[4];
  float* out = (float*)d_out;

  unsigned short* ws = (unsigned short*)d_ws;
  unsigned short* xb   = ws;                      // 4096*1024
  unsigned short* x2b  = xb   + 4096*1024;
  unsigned short* Wqb  = x2b  + 4096*1024;        // 1024*1024
  unsigned short* Wab  = Wqb  + 1024*1024;
  unsigned short* Wkvb = Wab  + 1024*1024;        // 2048*1024
  unsigned short* Qw   = Wkvb + 2048*1024;        // BHND = 4194304 each
  unsigned short* Aw   = Qw   + 4194304;
  unsigned short* Kw   = Aw   + 4194304;
  unsigned short* Vwt  = Kw   + 4194304;          // V^T [bh][d][n] (direct from gemm)
  unsigned short* Ywt  = xb;                      // Y^T [bh][d][n] (xb dead after gemm)

  cast_all<<<dim3(3072), dim3(256), 0, stream>>>(x, x2, Wq, Wa, Wkv, ws);

  gemm_all<<<dim3(1024), dim3(256), 0, stream>>>(xb, x2b, Wqb, Wab, Wkvb, Qw, Aw, Kw, Vwt);

  // pass 1: Y^T = (softmax(A k^T s) v)^T  -- written directly transposed
  attn_pass<<<dim3(512), dim3(512), 0, stream>>>(Aw, Kw, Vwt, Ywt, nullptr, 0);

  // pass 2: out = softmax(q A^T s) Y
  attn_pass<<<dim3(512), dim3(512), 0, stream>>>(Qw, Aw, Ywt, nullptr, out, 1);
}

// Round 13
// 147.346 us; speedup vs baseline: 13.4070x; 1.0145x over previous
//
#include <hip/hip_runtime.h>

#define DIM 1024
#define HEADS 16
#define HDIM 64
#define SEQ 2048
// 0.125 * log2(e) — folded into A's projection epilogue
#define SCLOG2 0.18033688011112042f

typedef __attribute__((ext_vector_type(8))) short short8;
typedef __attribute__((ext_vector_type(4))) float f32x4;
typedef __attribute__((ext_vector_type(16))) float f32x16;
typedef __attribute__((ext_vector_type(4))) int i32x4;

static __device__ __forceinline__ unsigned short f2bf(float f){
  union { float f; unsigned int u; } v; v.f = f;
  unsigned int r = v.u + 0x7fffu + ((v.u >> 16) & 1u);
  return (unsigned short)(r >> 16);
}

static __device__ __forceinline__ int cvtpk(float lo, float hi){
  int r;
  asm("v_cvt_pk_bf16_f32 %0, %1, %2" : "=v"(r) : "v"(lo), "v"(hi));
  return r;
}
static __device__ __forceinline__ void swap32(int& a, int& b){
  asm("v_permlane32_swap_b32 %0, %1" : "+v"(a), "+v"(b));
}

__device__ __forceinline__ void gl_lds16(const unsigned short* g, unsigned short* l){
  __builtin_amdgcn_global_load_lds((const __attribute__((address_space(1))) void*)g,
                                   (__attribute__((address_space(3))) void*)l, 16, 0, 0);
}

// ---------------- fused cast: all 5 inputs -> contiguous bf16 ws (HBM-peak, done) ------
#define CAST_TOTAL 3145728

__global__ __launch_bounds__(256)
void cast_all(const float* __restrict__ x, const float* __restrict__ x2,
              const float* __restrict__ wq, const float* __restrict__ wa,
              const float* __restrict__ wkv, unsigned short* __restrict__ out)
{
  for (int i = blockIdx.x*256 + threadIdx.x; i < CAST_TOTAL; i += gridDim.x*256){
    const float* src; int off;
    if      (i < 1048576){ src = x;   off = i; }
    else if (i < 2097152){ src = x2;  off = i - 1048576; }
    else if (i < 2359296){ src = wq;  off = i - 2097152; }
    else if (i < 2621440){ src = wa;  off = i - 2359296; }
    else                 { src = wkv; off = i - 2621440; }
    float4 v = ((const float4*)src)[off];
    ushort4 o;
    o.x = f2bf(v.x); o.y = f2bf(v.y); o.z = f2bf(v.z); o.w = f2bf(v.w);
    ((ushort4*)out)[i] = o;
  }
}

// ---------------- merged GEMM (R12-proven: dbuf + XOR swizzle + XCD stripes) — UNCHANGED
#define GK 1024

__global__ __launch_bounds__(256)
void gemm_all(const unsigned short* __restrict__ xb,  const unsigned short* __restrict__ x2b,
              const unsigned short* __restrict__ Wqb, const unsigned short* __restrict__ Wab,
              const unsigned short* __restrict__ Wkvb,
              unsigned short* __restrict__ Qw, unsigned short* __restrict__ Aw,
              unsigned short* __restrict__ Kw, unsigned short* __restrict__ Vwt)
{
  __shared__ unsigned short Ald[2][128*64];   // 32 KB
  __shared__ unsigned short Bld[2][128*64];   // 32 KB
  const int tid  = threadIdx.x;
  const int lane = tid & 63;
  const int wid  = tid >> 6;
  const int l15 = lane & 15, l4 = lane >> 4;
  const int wm = wid >> 1, wn = wid & 1;

  const int bid = blockIdx.x;
  const unsigned short *Abuf, *Bbuf;
  int mbase, nbase, isA;
  if (bid < 768){
    int xcd = bid & 7, s = bid >> 3;       // s 0..95
    int mb = xcd*4 + (s & 3);              // 0..31, disjoint stripes per XCD
    int nb = s >> 2;                       // 0..23
    nbase = nb*128; mbase = mb*128; isA = 0;
    Abuf = xb;
    Bbuf = (nbase < 1024) ? (Wqb + (size_t)nbase*GK) : (Wkvb + (size_t)(nbase-1024)*GK);
  } else {
    int b2 = bid - 768;                    // 0..255
    int xcd = b2 & 7, s = b2 >> 3;         // s 0..31
    int mb = xcd*4 + (s & 3);
    int nb = s >> 2;                       // 0..7
    nbase = nb*128; mbase = mb*128; isA = 1;
    Abuf = x2b;
    Bbuf = Wab + (size_t)nbase*GK;
  }
  const bool isV = (!isA) && (nbase >= 2048);

  const int srow = wid*32 + (lane >> 3);
  const int scol = ((lane & 7) ^ (lane >> 3)) * 8;   // pre-swizzled source column
  const unsigned short* gA = Abuf + (size_t)(mbase + srow)*GK + scol;
  const unsigned short* gB = Bbuf + (size_t)srow*GK + scol;

  const int rsw = (l15 & 7) * 8;

  f32x4 acc[4][4];
  #pragma unroll
  for (int i=0;i<4;i++)
    #pragma unroll
    for(int j=0;j<4;j++) acc[i][j] = (f32x4){0.f,0.f,0.f,0.f};

  #pragma unroll
  for (int i=0;i<4;++i){
    gl_lds16(gA + (size_t)(i*8)*GK, &Ald[0][(wid*32 + i*8)*64]);
    gl_lds16(gB + (size_t)(i*8)*GK, &Bld[0][(wid*32 + i*8)*64]);
  }
  asm volatile("s_waitcnt vmcnt(0)" ::: "memory");
  __builtin_amdgcn_s_barrier();
  __builtin_amdgcn_sched_barrier(0);

  for (int t = 0; t < 16; ++t){
    const int cur = t & 1;
    if (t+1 < 16){
      const int nxt = cur ^ 1;
      const int kt = (t+1)*64;
      #pragma unroll
      for (int i=0;i<4;++i){
        gl_lds16(gA + (size_t)(i*8)*GK + kt, &Ald[nxt][(wid*32 + i*8)*64]);
        gl_lds16(gB + (size_t)(i*8)*GK + kt, &Bld[nxt][(wid*32 + i*8)*64]);
      }
    }
    #pragma unroll
    for (int kc = 0; kc < 2; ++kc){
      short8 af[4], bf[4];
      #pragma unroll
      for (int mt=0; mt<4; ++mt)
        af[mt] = *(const short8*)(&Ald[cur][(wm*64 + mt*16 + l15)*64 + ((kc*32 + l4*8) ^ rsw)]);
      #pragma unroll
      for (int nt=0; nt<4; ++nt)
        bf[nt] = *(const short8*)(&Bld[cur][(wn*64 + nt*16 + l15)*64 + ((kc*32 + l4*8) ^ rsw)]);
      __builtin_amdgcn_s_setprio(1);
      if (isV){
        #pragma unroll
        for (int mt=0; mt<4; ++mt)
          #pragma unroll
          for (int nt=0; nt<4; ++nt)
            acc[mt][nt] = __builtin_amdgcn_mfma_f32_16x16x32_bf16(af[mt], bf[nt], acc[mt][nt], 0,0,0);
      } else {
        #pragma unroll
        for (int mt=0; mt<4; ++mt)
          #pragma unroll
          for (int nt=0; nt<4; ++nt)
            acc[mt][nt] = __builtin_amdgcn_mfma_f32_16x16x32_bf16(bf[nt], af[mt], acc[mt][nt], 0,0,0);
      }
      __builtin_amdgcn_s_setprio(0);
    }
    asm volatile("s_waitcnt vmcnt(0)" ::: "memory");
    __builtin_amdgcn_s_barrier();
    __builtin_amdgcn_sched_barrier(0);
  }

  if (!isV){
    unsigned short* dst = isA ? Aw : (nbase < 1024 ? Qw : Kw);
    const int coff = (!isA && nbase >= 1024) ? 1024 : 0;
    const float scale = isA ? SCLOG2 : 1.0f;
    #pragma unroll
    for (int mt=0; mt<4; ++mt){
      int token = mbase + wm*64 + mt*16 + l15;
      int b = token >> 11, n = token & 2047;
      #pragma unroll
      for (int nt=0; nt<4; ++nt){
        int colb = nbase - coff + wn*64 + nt*16 + l4*4;
        int h = colb >> 6, d = colb & 63;
        ushort4 pk;
        pk.x = f2bf(acc[mt][nt][0] * scale);
        pk.y = f2bf(acc[mt][nt][1] * scale);
        pk.z = f2bf(acc[mt][nt][2] * scale);
        pk.w = f2bf(acc[mt][nt][3] * scale);
        *(ushort4*)(dst + ((size_t)((b*HEADS + h)*SEQ + n))*HDIM + d) = pk;
      }
    }
  } else {
    #pragma unroll
    for (int mt=0; mt<4; ++mt){
      int mrow = mbase + wm*64 + mt*16 + l4*4;
      int b = mrow >> 11, nblk = mrow & 2047;
      #pragma unroll
      for (int nt=0; nt<4; ++nt){
        int col = nbase + wn*64 + nt*16 + l15;
        int c2 = col - 2048, h = c2 >> 6, d = c2 & 63;
        ushort4 pk;
        pk.x = f2bf(acc[mt][nt][0]);
        pk.y = f2bf(acc[mt][nt][1]);
        pk.z = f2bf(acc[mt][nt][2]);
        pk.w = f2bf(acc[mt][nt][3]);
        *(ushort4*)(Vwt + ((size_t)((b*HEADS + h)*HDIM + d))*SEQ + nblk) = pk;
      }
    }
  }
}

// ---------------- fused flash attention: KT2=32 tiles, 32 KB staging, 4 blocks/CU -------
// Q row-major [bh][q][d]; K row-major [bh][key][d]; V pre-transposed [bh][d][key]
// 8 waves: qw = wid&3 (32 q-rows each), kvh = wid>>2 (keys kvh*1024 .. +1024, 32 tiles of 32)
// Staging per kv-group per buf: K 4 frags (db 0..3) + V 4 frags (db2*2+kb2) = 4096 shorts.
// mode 0: writes Y^T [bh][d][q] bf16. mode 1: writes fp32 out[b][q][h*64+d].
#define KT2 32
#define NTH 32     // tiles per kv half

__global__ __launch_bounds__(512)
void attn_pass(const unsigned short* __restrict__ Qb,
               const unsigned short* __restrict__ Kb,
               const unsigned short* __restrict__ Vtb,
               unsigned short* __restrict__ ytb,
               float* __restrict__ outf,
               int mode)
{
  // staging 32 KB (2 groups x 2 bufs x 4096 shorts) overlaid by merge Of[128][68]f + Os[128]f
  __shared__ __align__(16) char SHRAW[35328];
  unsigned short* SH = (unsigned short*)SHRAW;
  const int tid = threadIdx.x, lane = tid & 63, wid = tid >> 6;  // 8 waves
  const int l31 = lane & 31, l5 = lane >> 5;
  const int qw = wid & 3, kvh = wid >> 2;

  // XCD-aware decode: 4 bh per XCD, all 16 q-blocks of a bh on one XCD
  const int bid = blockIdx.x;
  const int cx = bid & 7, j = bid >> 3;
  const int bh = cx*4 + (j >> 4);
  const int qb = j & 15;
  const int q0 = qb*128 + qw*32;               // this wave's 32 q-rows
  const size_t base = (size_t)bh * SEQ * HDIM;

  // Q^T B-fragments (col q = l31, k-rows d = db*16 + l5*8 ..+8)
  short8 qf[4];
  #pragma unroll
  for (int db=0; db<4; ++db)
    qf[db] = *(const short8*)(Qb + base + (size_t)(q0 + l31)*HDIM + db*16 + l5*8);

  // staging duty: qw0,1 -> K frags db {0,1},{2,3}; qw2,3 -> V frags db2 {0},{1} x kb2 {0,1}
  const unsigned short* gsrc[2];
  int ldst[2];
  int sstep;
  const int grpoff = kvh * 8192;               // shorts
  if (qw < 2){
    #pragma unroll
    for (int f=0; f<2; ++f){
      gsrc[f] = Kb + base + (size_t)(kvh*1024 + l31)*HDIM + (qw*2 + f)*16 + l5*8;
      ldst[f] = grpoff + (qw*2 + f)*512;
    }
    sstep = KT2*HDIM;
  } else {
    const int db2 = qw - 2;
    #pragma unroll
    for (int f=0; f<2; ++f){
      gsrc[f] = Vtb + base + (size_t)(db2*32 + l31)*SEQ + kvh*1024 + f*16 + l5*8;
      ldst[f] = grpoff + 2048 + (db2*2 + f)*512;
    }
    sstep = KT2;
  }

  f32x16 oo0, oo1, ssum;
  #pragma unroll
  for (int r=0;r<16;++r){ oo0[r]=0.f; oo1[r]=0.f; ssum[r]=0.f; }
  short8 ones;
  #pragma unroll
  for (int jj=0;jj<8;++jj) ones[jj] = (short)0x3F80;

  #pragma unroll
  for (int f=0; f<2; ++f)
    gl_lds16(gsrc[f], SH + ldst[f]);
  asm volatile("s_waitcnt vmcnt(0)" ::: "memory");
  __builtin_amdgcn_s_barrier();
  __builtin_amdgcn_sched_barrier(0);

  for (int t = 0; t < NTH; ++t){
    const int cur = t & 1;
    if (t+1 < NTH){
      const int pbuf = ((t+1) & 1) * 4096;
      #pragma unroll
      for (int f=0; f<2; ++f)
        gl_lds16(gsrc[f] + (size_t)(t+1)*sstep, SH + ldst[f] + pbuf);
    }
    const unsigned short* Kc = SH + grpoff + cur*4096;
    const unsigned short* Vc = Kc + 2048;

    // S^T = K * Q^T : lane = col q0+l31, rows key = (r&3)+8*(r>>2)+4*l5 (32-key tile)
    f32x16 sacc;
    #pragma unroll
    for (int r=0;r<16;++r) sacc[r]=0.f;
    __builtin_amdgcn_s_setprio(1);
    #pragma unroll
    for (int db=0; db<4; ++db){
      short8 kfr = *(const short8*)(Kc + db*512 + lane*8);
      sacc = __builtin_amdgcn_mfma_f32_32x32x16_bf16(kfr, qf[db], sacc, 0,0,0);
    }
    __builtin_amdgcn_s_setprio(0);
    float p[16];
    #pragma unroll
    for (int r=0;r<16;++r)
      p[r] = __builtin_amdgcn_exp2f(sacc[r]);   // scale pre-folded into A projection

    // build P^T B-frags in registers; PV + ones-MFMA rowsum
    #pragma unroll
    for (int kb2=0; kb2<2; ++kb2){
      const int pb = kb2*8;
      int a0 = cvtpk(p[pb+0], p[pb+1]);
      int b0 = cvtpk(p[pb+4], p[pb+5]);
      int a1 = cvtpk(p[pb+2], p[pb+3]);
      int b1 = cvtpk(p[pb+6], p[pb+7]);
      swap32(a0, b0);
      swap32(a1, b1);
      i32x4 pav; pav[0]=a0; pav[1]=a1; pav[2]=b0; pav[3]=b1;
      short8 paf = *(short8*)&pav;
      __builtin_amdgcn_s_setprio(1);
      ssum = __builtin_amdgcn_mfma_f32_32x32x16_bf16(ones, paf, ssum, 0,0,0);
      short8 v0 = *(const short8*)(Vc + (0*2+kb2)*512 + lane*8);
      oo0 = __builtin_amdgcn_mfma_f32_32x32x16_bf16(v0, paf, oo0, 0,0,0);
      short8 v1 = *(const short8*)(Vc + (1*2+kb2)*512 + lane*8);
      oo1 = __builtin_amdgcn_mfma_f32_32x32x16_bf16(v1, paf, oo1, 0,0,0);
      __builtin_amdgcn_s_setprio(0);
    }

    asm volatile("s_waitcnt vmcnt(0)" ::: "memory");
    __builtin_amdgcn_s_barrier();
    __builtin_amdgcn_sched_barrier(0);
  }

  // ---- in-block merge of the two kv halves ----
  float* Of  = (float*)SHRAW;                 // [128][68]
  float* Os1 = (float*)(SHRAW + 128*68*4);    // [128]
  const int ql = qw*32 + l31;

  if (kvh == 1){
    #pragma unroll
    for (int g=0; g<4; ++g){
      f32x4 w0, w1;
      #pragma unroll
      for (int r=0;r<4;++r){ w0[r] = oo0[g*4+r]; w1[r] = oo1[g*4+r]; }
      int d0 = 8*g + 4*l5;
      *(f32x4*)(Of + ql*68 + d0)      = w0;
      *(f32x4*)(Of + ql*68 + d0 + 32) = w1;
    }
    Os1[ql] = ssum[0];
  }
  __syncthreads();

  if (kvh == 0){
    const float rinv = 1.0f / (ssum[0] + Os1[ql]);
    if (mode == 0){
      #pragma unroll
      for (int r=0;r<16;++r){
        int d0 = (r&3) + 8*(r>>2) + 4*l5;
        float f0 = (oo0[r] + Of[ql*68 + d0])      * rinv;
        float f1 = (oo1[r] + Of[ql*68 + d0 + 32]) * rinv;
        ytb[base + (size_t)(d0)*SEQ + q0 + l31]    = f2bf(f0);
        ytb[base + (size_t)(d0+32)*SEQ + q0 + l31] = f2bf(f1);
      }
    } else {
      #pragma unroll
      for (int g=0; g<4; ++g){
        int d0 = 8*g + 4*l5;
        f32x4 w0 = *(const f32x4*)(Of + ql*68 + d0);
        f32x4 w1 = *(const f32x4*)(Of + ql*68 + d0 + 32);
        #pragma unroll
        for (int r=0;r<4;++r){ w0[r] = (w0[r]+oo0[g*4+r])*rinv; w1[r] = (w1[r]+oo1[g*4+r])*rinv; }
        *(f32x4*)(Of + ql*68 + d0)      = w0;
        *(f32x4*)(Of + ql*68 + d0 + 32) = w1;
      }
    }
  }

  if (mode == 1){
    __syncthreads();
    const int b = bh >> 4, h = bh & 15;
    const int qr = tid >> 2, dh = (tid & 3)*16;
    const float* src = Of + qr*68 + dh;
    float* drow = outf + ((size_t)(b*SEQ + qb*128 + qr))*DIM + h*HDIM + dh;
    #pragma unroll
    for (int k2=0;k2<4;++k2)
      *(float4*)(drow + k2*4) = *(const float4*)(src + k2*4);
  }
}

extern "C" void kernel_launch(void* const* d_in, const int* in_sizes, int n_in,
                              void* d_out, int out_size, void* d_ws, size_t ws_size,
                              hipStream_t stream) {
  const float* x   = (const float*)d_in[0];
  const float* x2  = (const float*)d_in[1];
  const float* Wq  = (const float*)d_in[2];
  const float* Wa  = (const float*)d_in[3];
  const float* Wkv = (const float*)d_in[4];
  float* out = (float*)d_out;

  unsigned short* ws = (unsigned short*)d_ws;
  unsigned short* xb   = ws;                      // 4096*1024
  unsigned short* x2b  = xb   + 4096*1024;
  unsigned short* Wqb  = x2b  + 4096*1024;        // 1024*1024
  unsigned short* Wab  = Wqb  + 1024*1024;
  unsigned short* Wkvb = Wab  + 1024*1024;        // 2048*1024
  unsigned short* Qw   = Wkvb + 2048*1024;        // BHND = 4194304 each
  unsigned short* Aw   = Qw   + 4194304;
  unsigned short* Kw   = Aw   + 4194304;
  unsigned short* Vwt  = Kw   + 4194304;          // V^T [bh][d][n] (direct from gemm)
  unsigned short* Ywt  = xb;                      // Y^T [bh][d][n] (xb dead after gemm)

  cast_all<<<dim3(3072), dim3(256), 0, stream>>>(x, x2, Wq, Wa, Wkv, ws);

  gemm_all<<<dim3(1024), dim3(256), 0, stream>>>(xb, x2b, Wqb, Wab, Wkvb, Qw, Aw, Kw, Vwt);

  // pass 1: Y^T = (softmax(A k^T s) v)^T  -- written directly transposed
  attn_pass<<<dim3(512), dim3(512), 0, stream>>>(Aw, Kw, Vwt, Ywt, nullptr, 0);

  // pass 2: out = softmax(q A^T s) Y
  attn_pass<<<dim3(512), dim3(512), 0, stream>>>(Qw, Aw, Ywt, nullptr, out, 1);
}